// Round 9
// baseline (489.515 us; speedup 1.0000x reference)
//
#include <hip/hip_runtime.h>
#include <math.h>

// ---------------------------------------------------------------------------
// SpatialGCN:
//  * CSR (dst-grouped, UNORDERED groups) built via hist -> block-scan
//    reservation -> scatter. No serial device scan.
//  * Per layer: edge-parallel contribution kernel (plain stores, no atomics)
//    + node segmented-sum kernel (4 threads/node).
//  * Self-loops + bias folded into segsum via Wself.
//  * R7: inner math hand-written as VOP3P packed fp32 (v_pk_fma_f32 etc.)
//    with op_sel broadcasts; weights bound as "s" operands (scalar path).
// ---------------------------------------------------------------------------

typedef __attribute__((ext_vector_type(2))) float f32x2;

struct WPtrs {
    const float* bin0; const float* wout0;
    const float* bin1; const float* wout1;
    const float* bin2; const float* wout2;
};

// Extract packed pos (N x 2) and feat (N x 16) from x (N x 18).
__global__ __launch_bounds__(256) void prep_kernel(
    const float* __restrict__ x, float* __restrict__ pos,
    float* __restrict__ feat, int n)
{
    int i = blockIdx.x * 256 + threadIdx.x;
    if (i >= n) return;
    const float* r = x + (size_t)i * 18;
    float2 p; p.x = r[0]; p.y = r[1];
    ((float2*)pos)[i] = p;
    float4* fp = (float4*)feat + (size_t)i * 4;
    fp[0] = make_float4(r[2],  r[3],  r[4],  r[5]);
    fp[1] = make_float4(r[6],  r[7],  r[8],  r[9]);
    fp[2] = make_float4(r[10], r[11], r[12], r[13]);
    fp[3] = make_float4(r[14], r[15], r[16], r[17]);
}

// zero counts[n] and the global cursor total (ws is 0xAA-poisoned each call)
__global__ __launch_bounds__(256) void zero_kernel(int* __restrict__ p, int* __restrict__ total, int n)
{
    int i = blockIdx.x * 256 + threadIdx.x;
    if (i < n) p[i] = 0;
    if (i == 0) *total = 0;
}

__global__ __launch_bounds__(256) void hist_kernel(
    const int* __restrict__ ei, int* __restrict__ counts, int E)
{
    int e = blockIdx.x * 256 + threadIdx.x;
    if (e < E) atomicAdd(&counts[ei[E + e]], 1);
}

// Parallel slot reservation: per-block LDS inclusive scan of 256 counts,
// one global atomicAdd per block, write start/cursor.
__global__ __launch_bounds__(256) void reserve_kernel(
    const int* __restrict__ counts, int* __restrict__ start,
    int* __restrict__ cursor, int* __restrict__ total, int n)
{
    __shared__ int sdata[256];
    __shared__ int sbase;
    int t = threadIdx.x;
    int i = blockIdx.x * 256 + t;
    int c = (i < n) ? counts[i] : 0;
    sdata[t] = c;
    __syncthreads();
    #pragma unroll
    for (int off = 1; off < 256; off <<= 1) {
        int v = (t >= off) ? sdata[t - off] : 0;
        __syncthreads();
        sdata[t] += v;
        __syncthreads();
    }
    if (t == 255) sbase = atomicAdd(total, sdata[255]);
    __syncthreads();
    if (i < n) {
        int s = sbase + sdata[t] - c;   // block base + exclusive prefix
        start[i]  = s;
        cursor[i] = s;
    }
}

// Scatter edges into dst-grouped order; precompute rel per sorted edge.
__global__ __launch_bounds__(256) void scatter_kernel(
    const int* __restrict__ ei, const float* __restrict__ pos,
    int* __restrict__ cursor, int* __restrict__ ssrc,
    float2* __restrict__ srel, int E)
{
    int e = blockIdx.x * 256 + threadIdx.x;
    if (e >= E) return;
    int s = ei[e];
    int d = ei[E + e];
    int p = atomicAdd(&cursor[d], 1);
    ssrc[p] = s;
    float2 ps = ((const float2*)pos)[s];
    float2 pd = ((const float2*)pos)[d];
    srel[p] = make_float2(ps.x - pd.x, ps.y - pd.y);
}

// Wself[l][c*16+o] = sum_h relu(bin[h*16+c]) * Wout[(h*16+c)*16+o]
__global__ __launch_bounds__(256) void wself_kernel(WPtrs wp, float* __restrict__ wself)
{
    int l = blockIdx.x;
    const float* bin  = (l == 0) ? wp.bin0  : (l == 1) ? wp.bin1  : wp.bin2;
    const float* wout = (l == 0) ? wp.wout0 : (l == 1) ? wp.wout1 : wp.wout2;
    int t = threadIdx.x;          // t = c*16 + o
    int c = t >> 4, o = t & 15;
    float acc = 0.f;
    #pragma unroll
    for (int h = 0; h < 16; ++h) {
        int hc = h * 16 + c;
        acc += fmaxf(bin[hc], 0.f) * wout[hc * 16 + o];
    }
    wself[l * 256 + t] = acc;
}

// One thread per grouped edge slot: contribution = (relu(rel@Win+bin)*xj)@Wout,
// written to contrib[p][0..16) with plain stores. VOP3P packed-fp32 inner math.
__global__ __launch_bounds__(256) void edge_contrib_kernel(
    const int* __restrict__ ssrc,   // [E] grouped src
    const float2* __restrict__ srel,// [E] grouped rel
    const float* __restrict__ fin,  // [N,16]
    const float* __restrict__ Win,  // [2,256]
    const float* __restrict__ bin,  // [256]
    const float* __restrict__ Wout, // [256,16]
    float* __restrict__ contrib,    // [E,16]
    int E)
{
    int p = blockIdx.x * 256 + threadIdx.x;
    bool valid = (p < E);
    int pp = valid ? p : 0;
    int s = ssrc[pp];
    float2 r = srel[pp];

    const float4* fp = (const float4*)fin + (size_t)s * 4;
    float4 a = fp[0], b = fp[1], c4 = fp[2], d4 = fp[3];
    f32x2 xj2[8] = { {a.x,a.y}, {a.z,a.w}, {b.x,b.y}, {b.z,b.w},
                     {c4.x,c4.y}, {c4.z,c4.w}, {d4.x,d4.y}, {d4.z,d4.w} };

    f32x2 rxy = { r.x, r.y };

    f32x2 acc2[8];
    #pragma unroll
    for (int j = 0; j < 8; ++j) acc2[j] = (f32x2){0.f, 0.f};

    // h-loop kept rolled to bound SGPR live ranges; c2 fully unrolled.
    #pragma unroll 1
    for (int h = 0; h < 16; ++h) {
        #pragma unroll
        for (int c2 = 0; c2 < 8; ++c2) {
            int hc = h * 16 + c2 * 2;               // even -> aligned pairs
            f32x2 w1 = *(const f32x2*)(Win + hc);
            f32x2 w2 = *(const f32x2*)(Win + 256 + hc);
            f32x2 b2 = *(const f32x2*)(bin + hc);
            f32x2 u;
            // u = rx * w1           (broadcast rxy.lo to both halves)
            asm("v_pk_mul_f32 %0, %1, %2 op_sel:[0,0] op_sel_hi:[0,1]"
                : "=v"(u) : "v"(rxy), "s"(w1));
            // u += ry * w2          (broadcast rxy.hi)
            asm("v_pk_fma_f32 %0, %1, %2, %0 op_sel:[1,0,0] op_sel_hi:[1,1,1]"
                : "+v"(u) : "v"(rxy), "s"(w2));
            // u += bin pair
            asm("v_pk_add_f32 %0, %0, %1" : "+v"(u) : "s"(b2));
            // relu + scale by xj (no v_pk_max_f32 exists -> scalar halves)
            f32x2 t;
            t.x = fmaxf(u.x, 0.f) * xj2[c2].x;
            t.y = fmaxf(u.y, 0.f) * xj2[c2].y;
            const f32x2* wr0 = (const f32x2*)(Wout + (size_t)hc * 16);
            const f32x2* wr1 = (const f32x2*)(Wout + (size_t)(hc + 1) * 16);
            // acc += t.x * Wout[hc]   (op_sel broadcasts t.lo)
            #pragma unroll
            for (int j = 0; j < 8; ++j)
                asm("v_pk_fma_f32 %0, %1, %2, %0 op_sel:[0,0,0] op_sel_hi:[0,1,1]"
                    : "+v"(acc2[j]) : "v"(t), "s"(wr0[j]));
            // acc += t.y * Wout[hc+1] (op_sel broadcasts t.hi)
            #pragma unroll
            for (int j = 0; j < 8; ++j)
                asm("v_pk_fma_f32 %0, %1, %2, %0 op_sel:[1,0,0] op_sel_hi:[1,1,1]"
                    : "+v"(acc2[j]) : "v"(t), "s"(wr1[j]));
        }
    }

    if (valid) {
        float4* op = (float4*)(contrib + (size_t)p * 16);
        op[0] = make_float4(acc2[0].x, acc2[0].y, acc2[1].x, acc2[1].y);
        op[1] = make_float4(acc2[2].x, acc2[2].y, acc2[3].x, acc2[3].y);
        op[2] = make_float4(acc2[4].x, acc2[4].y, acc2[5].x, acc2[5].y);
        op[3] = make_float4(acc2[6].x, acc2[6].y, acc2[7].x, acc2[7].y);
    }
}

// 4 threads per node, one float4 channel-quad each. Init = bias + self-loop
// (fin[node] @ Wself), then sum grouped contributions over [start, start+cnt).
__global__ __launch_bounds__(256) void segsum_kernel(
    const int* __restrict__ start, const int* __restrict__ counts,
    const float* __restrict__ contrib,
    const float* __restrict__ fin, const float* __restrict__ wself,
    const float* __restrict__ bout, float* __restrict__ out, int n)
{
    int tid = blockIdx.x * 256 + threadIdx.x;
    int node = tid >> 2;
    int q = tid & 3;            // channel quad index
    if (node >= n) return;

    const float4* ip = (const float4*)fin + (size_t)node * 4;
    float4 f0 = ip[0], f1 = ip[1], f2 = ip[2], f3 = ip[3];
    float xin[16] = { f0.x,f0.y,f0.z,f0.w, f1.x,f1.y,f1.z,f1.w,
                      f2.x,f2.y,f2.z,f2.w, f3.x,f3.y,f3.z,f3.w };

    float4 bi = ((const float4*)bout)[q];
    f32x2 accA = { bi.x, bi.y };
    f32x2 accB = { bi.z, bi.w };
    #pragma unroll
    for (int c = 0; c < 16; ++c) {
        f32x2 tt = { xin[c], xin[c] };
        const f32x2* w = (const f32x2*)(wself + c * 16) + q * 2;
        asm("v_pk_fma_f32 %0, %1, %2, %0" : "+v"(accA) : "v"(tt), "s"(w[0]));
        asm("v_pk_fma_f32 %0, %1, %2, %0" : "+v"(accB) : "v"(tt), "s"(w[1]));
    }

    int b = start[node];
    int e = b + counts[node];
    for (int k = b; k < e; ++k) {
        float4 v = ((const float4*)contrib)[(size_t)k * 4 + q];
        accA.x += v.x; accA.y += v.y;
        accB.x += v.z; accB.y += v.w;
    }

    ((float4*)(out + (size_t)node * 16))[q] =
        make_float4(accA.x, accA.y, accB.x, accB.y);
}

// Edge MLP: sigmoid(relu(relu([h_s,h_d]@Wd1+b1)@Wd2+b2)@Wd3+b3) — packed fp32.
__global__ __launch_bounds__(256) void decode_kernel(
    const int* __restrict__ ei, const float* __restrict__ h,
    const float* __restrict__ Wd1, const float* __restrict__ bd1,
    const float* __restrict__ Wd2, const float* __restrict__ bd2,
    const float* __restrict__ Wd3, const float* __restrict__ bd3,
    float* __restrict__ out, int E)
{
    int tid = blockIdx.x * 256 + threadIdx.x;
    bool valid = (tid < E);
    int e = valid ? tid : 0;
    int s = ei[e];
    int d = ei[E + e];

    const float4* hp = (const float4*)h + (size_t)s * 4;
    float4 a = hp[0], b = hp[1], c4 = hp[2], d4 = hp[3];
    float hs[16] = { a.x,a.y,a.z,a.w, b.x,b.y,b.z,b.w,
                     c4.x,c4.y,c4.z,c4.w, d4.x,d4.y,d4.z,d4.w };
    const float4* hq = (const float4*)h + (size_t)d * 4;
    float4 e0 = hq[0], e1 = hq[1], e2 = hq[2], e3 = hq[3];
    float hd[16] = { e0.x,e0.y,e0.z,e0.w, e1.x,e1.y,e1.z,e1.w,
                     e2.x,e2.y,e2.z,e2.w, e3.x,e3.y,e3.z,e3.w };

    f32x2 z1[8];
    #pragma unroll
    for (int j = 0; j < 8; ++j) z1[j] = *((const f32x2*)bd1 + j);
    #pragma unroll
    for (int c = 0; c < 16; ++c) {
        f32x2 uv = { hs[c], hd[c] };
        const f32x2* wu = (const f32x2*)(Wd1 + (size_t)c * 16);
        const f32x2* wv = (const f32x2*)(Wd1 + (size_t)(16 + c) * 16);
        #pragma unroll
        for (int j = 0; j < 8; ++j)
            asm("v_pk_fma_f32 %0, %1, %2, %0 op_sel:[0,0,0] op_sel_hi:[0,1,1]"
                : "+v"(z1[j]) : "v"(uv), "s"(wu[j]));
        #pragma unroll
        for (int j = 0; j < 8; ++j)
            asm("v_pk_fma_f32 %0, %1, %2, %0 op_sel:[1,0,0] op_sel_hi:[1,1,1]"
                : "+v"(z1[j]) : "v"(uv), "s"(wv[j]));
    }
    float z1s[16];
    #pragma unroll
    for (int j = 0; j < 8; ++j) {
        z1s[2*j]   = fmaxf(z1[j].x, 0.f);
        z1s[2*j+1] = fmaxf(z1[j].y, 0.f);
    }

    f32x2 z2[8];
    #pragma unroll
    for (int j = 0; j < 8; ++j) z2[j] = *((const f32x2*)bd2 + j);
    #pragma unroll
    for (int c2 = 0; c2 < 8; ++c2) {
        f32x2 tt = { z1s[2*c2], z1s[2*c2+1] };
        const f32x2* w0 = (const f32x2*)(Wd2 + (size_t)(2*c2) * 16);
        const f32x2* w1 = (const f32x2*)(Wd2 + (size_t)(2*c2+1) * 16);
        #pragma unroll
        for (int j = 0; j < 8; ++j)
            asm("v_pk_fma_f32 %0, %1, %2, %0 op_sel:[0,0,0] op_sel_hi:[0,1,1]"
                : "+v"(z2[j]) : "v"(tt), "s"(w0[j]));
        #pragma unroll
        for (int j = 0; j < 8; ++j)
            asm("v_pk_fma_f32 %0, %1, %2, %0 op_sel:[1,0,0] op_sel_hi:[1,1,1]"
                : "+v"(z2[j]) : "v"(tt), "s"(w1[j]));
    }

    float y = bd3[0];
    #pragma unroll
    for (int j = 0; j < 8; ++j) {
        y = fmaf(fmaxf(z2[j].x, 0.f), Wd3[2*j],   y);
        y = fmaf(fmaxf(z2[j].y, 0.f), Wd3[2*j+1], y);
    }

    if (valid)
        out[tid] = 1.f / (1.f + expf(-y));
}

extern "C" void kernel_launch(void* const* d_in, const int* in_sizes, int n_in,
                              void* d_out, int out_size, void* d_ws, size_t ws_size,
                              hipStream_t stream)
{
    const float* x     = (const float*)d_in[0];
    const int*   ei    = (const int*)  d_in[1];
    const float* Win1  = (const float*)d_in[2];
    const float* bin1  = (const float*)d_in[3];
    const float* Wout1 = (const float*)d_in[4];
    const float* bout1 = (const float*)d_in[5];
    const float* Win2  = (const float*)d_in[6];
    const float* bin2  = (const float*)d_in[7];
    const float* Wout2 = (const float*)d_in[8];
    const float* bout2 = (const float*)d_in[9];
    const float* Win3  = (const float*)d_in[10];
    const float* bin3  = (const float*)d_in[11];
    const float* Wout3 = (const float*)d_in[12];
    const float* bout3 = (const float*)d_in[13];
    const float* Wd1   = (const float*)d_in[14];
    const float* bd1   = (const float*)d_in[15];
    const float* Wd2   = (const float*)d_in[16];
    const float* bd2   = (const float*)d_in[17];
    const float* Wd3   = (const float*)d_in[18];
    const float* bd3   = (const float*)d_in[19];

    int n = in_sizes[0] / 18;
    int E = in_sizes[1] / 2;

    float* ws      = (float*)d_ws;
    float* pos     = ws;                        // 2n
    float* feat    = pos   + (size_t)2 * n;     // 16n
    float* hA      = feat  + (size_t)16 * n;    // 16n
    float* hB      = hA    + (size_t)16 * n;    // 16n
    float* wself   = hB    + (size_t)16 * n;    // 768
    int* counts    = (int*)(wself + 768);       // n
    int* start     = counts + n;                // n
    int* cursor    = start + n;                 // n
    int* total     = cursor + n;                // 1 (+1 pad -> 8B align)
    int* ssrc      = total + 2;                 // E
    float2* srel   = (float2*)(ssrc + E);       // E (8B aligned)
    float* contrib = (float*)(srel + E);        // 16E (32 MB, reused per layer)
    float* outp    = (float*)d_out;

    int nb_n  = (n + 255) / 256;
    int nb_e  = (E + 255) / 256;
    int nb_s  = (4 * n + 255) / 256;

    prep_kernel<<<nb_n, 256, 0, stream>>>(x, pos, feat, n);
    zero_kernel<<<nb_n, 256, 0, stream>>>(counts, total, n);
    hist_kernel<<<nb_e, 256, 0, stream>>>(ei, counts, E);
    reserve_kernel<<<nb_n, 256, 0, stream>>>(counts, start, cursor, total, n);
    scatter_kernel<<<nb_e, 256, 0, stream>>>(ei, pos, cursor, ssrc, srel, E);

    WPtrs wp { bin1, Wout1, bin2, Wout2, bin3, Wout3 };
    wself_kernel<<<3, 256, 0, stream>>>(wp, wself);

    // Layer 1: feat -> hA
    edge_contrib_kernel<<<nb_e, 256, 0, stream>>>(ssrc, srel, feat, Win1, bin1, Wout1, contrib, E);
    segsum_kernel<<<nb_s, 256, 0, stream>>>(start, counts, contrib, feat, wself + 0,   bout1, hA, n);
    // Layer 2: hA -> hB
    edge_contrib_kernel<<<nb_e, 256, 0, stream>>>(ssrc, srel, hA,   Win2, bin2, Wout2, contrib, E);
    segsum_kernel<<<nb_s, 256, 0, stream>>>(start, counts, contrib, hA,   wself + 256, bout2, hB, n);
    // Layer 3: hB -> hA
    edge_contrib_kernel<<<nb_e, 256, 0, stream>>>(ssrc, srel, hB,   Win3, bin3, Wout3, contrib, E);
    segsum_kernel<<<nb_s, 256, 0, stream>>>(start, counts, contrib, hB,   wself + 512, bout3, hA, n);

    decode_kernel<<<nb_e, 256, 0, stream>>>(ei, hA, Wd1, bd1, Wd2, bd2, Wd3, bd3,
                                            outp, E);
}

// Round 10
// 414.644 us; speedup vs baseline: 1.1806x; 1.1806x over previous
//
#include <hip/hip_runtime.h>
#include <math.h>

// ---------------------------------------------------------------------------
// SpatialGCN:
//  * CSR (dst-grouped, UNORDERED groups) built via hist -> block-scan
//    reservation -> scatter.
//  * Per layer: edge-parallel MFMA contribution kernel (one wave = 16 edges,
//    (s*xj)@Wout via mfma_f32_16x16x32_bf16 with 3-term bf16 split for fp32
//    precision) + scalar segmented-sum kernel (4 threads/node).
//  * Self-loops + bias folded into segsum via Wself.
//  * R10 lesson (R9 counters): scalar v_fma_f32 already saturates the fp32
//    pipe (157 TF = 2cyc/wave64 FMA); packed fp32 gains nothing. The matvec
//    must move to the matrix pipe.
// ---------------------------------------------------------------------------

typedef __attribute__((ext_vector_type(8))) short bf16x8;
typedef __attribute__((ext_vector_type(4))) float f32x4;

struct WPtrs {
    const float* bin0; const float* wout0;
    const float* bin1; const float* wout1;
    const float* bin2; const float* wout2;
};

__device__ __forceinline__ unsigned cvtpk_bf16(float a, float b) {
    unsigned r;
    asm("v_cvt_pk_bf16_f32 %0, %1, %2" : "=v"(r) : "v"(a), "v"(b));
    return r;   // r[15:0] = bf16(a), r[31:16] = bf16(b)
}

// Extract packed pos (N x 2) and feat (N x 16) from x (N x 18).
__global__ __launch_bounds__(256) void prep_kernel(
    const float* __restrict__ x, float* __restrict__ pos,
    float* __restrict__ feat, int n)
{
    int i = blockIdx.x * 256 + threadIdx.x;
    if (i >= n) return;
    const float* r = x + (size_t)i * 18;
    float2 p; p.x = r[0]; p.y = r[1];
    ((float2*)pos)[i] = p;
    float4* fp = (float4*)feat + (size_t)i * 4;
    fp[0] = make_float4(r[2],  r[3],  r[4],  r[5]);
    fp[1] = make_float4(r[6],  r[7],  r[8],  r[9]);
    fp[2] = make_float4(r[10], r[11], r[12], r[13]);
    fp[3] = make_float4(r[14], r[15], r[16], r[17]);
}

__global__ __launch_bounds__(256) void zero_kernel(int* __restrict__ p, int* __restrict__ total, int n)
{
    int i = blockIdx.x * 256 + threadIdx.x;
    if (i < n) p[i] = 0;
    if (i == 0) *total = 0;
}

__global__ __launch_bounds__(256) void hist_kernel(
    const int* __restrict__ ei, int* __restrict__ counts, int E)
{
    int e = blockIdx.x * 256 + threadIdx.x;
    if (e < E) atomicAdd(&counts[ei[E + e]], 1);
}

// Parallel slot reservation: per-block LDS inclusive scan of 256 counts,
// one global atomicAdd per block, write start/cursor.
__global__ __launch_bounds__(256) void reserve_kernel(
    const int* __restrict__ counts, int* __restrict__ start,
    int* __restrict__ cursor, int* __restrict__ total, int n)
{
    __shared__ int sdata[256];
    __shared__ int sbase;
    int t = threadIdx.x;
    int i = blockIdx.x * 256 + t;
    int c = (i < n) ? counts[i] : 0;
    sdata[t] = c;
    __syncthreads();
    #pragma unroll
    for (int off = 1; off < 256; off <<= 1) {
        int v = (t >= off) ? sdata[t - off] : 0;
        __syncthreads();
        sdata[t] += v;
        __syncthreads();
    }
    if (t == 255) sbase = atomicAdd(total, sdata[255]);
    __syncthreads();
    if (i < n) {
        int s = sbase + sdata[t] - c;
        start[i]  = s;
        cursor[i] = s;
    }
}

// Scatter edges into dst-grouped order; precompute rel per sorted edge.
__global__ __launch_bounds__(256) void scatter_kernel(
    const int* __restrict__ ei, const float* __restrict__ pos,
    int* __restrict__ cursor, int* __restrict__ ssrc,
    float2* __restrict__ srel, int E)
{
    int e = blockIdx.x * 256 + threadIdx.x;
    if (e >= E) return;
    int s = ei[e];
    int d = ei[E + e];
    int p = atomicAdd(&cursor[d], 1);
    ssrc[p] = s;
    float2 ps = ((const float2*)pos)[s];
    float2 pd = ((const float2*)pos)[d];
    srel[p] = make_float2(ps.x - pd.x, ps.y - pd.y);
}

// Wself[l][c*16+o] = sum_h relu(bin[h*16+c]) * Wout[(h*16+c)*16+o]
__global__ __launch_bounds__(256) void wself_kernel(WPtrs wp, float* __restrict__ wself)
{
    int l = blockIdx.x;
    const float* bin  = (l == 0) ? wp.bin0  : (l == 1) ? wp.bin1  : wp.bin2;
    const float* wout = (l == 0) ? wp.wout0 : (l == 1) ? wp.wout1 : wp.wout2;
    int t = threadIdx.x;
    int c = t >> 4, o = t & 15;
    float acc = 0.f;
    #pragma unroll
    for (int h = 0; h < 16; ++h) {
        int hc = h * 16 + c;
        acc += fmaxf(bin[hc], 0.f) * wout[hc * 16 + o];
    }
    wself[l * 256 + t] = acc;
}

// Pre-split Wout into per-lane bf16 B-fragments (hi and lo parts).
// Layout: bsplit[((layer*2 + part)*8 + kb)*256 + lane*4 + j]  (u32, 2 bf16).
// Lane's B element: B[k = kb*32 + (lane>>4)*8 + 2j + {0,1}][o = lane&15].
__global__ __launch_bounds__(256) void wsplit_kernel(WPtrs wp, unsigned* __restrict__ bsplit)
{
    int l = blockIdx.x;
    const float* wout = (l == 0) ? wp.wout0 : (l == 1) ? wp.wout1 : wp.wout2;
    int tid = threadIdx.x;
    int lane = tid & 63;
    int j = tid >> 6;          // 0..3
    int o = lane & 15, q = lane >> 4;
    for (int kb = 0; kb < 8; ++kb) {
        int k0 = kb * 32 + q * 8 + 2 * j;
        float v0 = wout[k0 * 16 + o];
        float v1 = wout[(k0 + 1) * 16 + o];
        unsigned hp = cvtpk_bf16(v0, v1);
        float h0 = __uint_as_float(hp << 16);
        float h1 = __uint_as_float(hp & 0xFFFF0000u);
        unsigned lp = cvtpk_bf16(v0 - h0, v1 - h1);
        int base = ((l * 2 + 0) * 8 + kb) * 256 + lane * 4 + j;
        bsplit[base] = hp;
        bsplit[base + 8 * 256] = lp;
    }
}

// One wave = 16 edges. A[e][k=hc] = relu(rel.Win+bin)[hc]*xj[c], B = Wout.
// D = A@B via 16x16x32 bf16 MFMA, 3-term split: AhiBhi + AloBhi + AhiBlo.
// A-frag: row = lane&15 (edge), k = kb*32 + (lane>>4)*8 + i (even k in lo half).
// D: row(edge) = (lane>>4)*4 + reg, col(o) = lane&15.   [m89-verified C/D]
__global__ __launch_bounds__(256) void edge_mfma_kernel(
    const int* __restrict__ ssrc, const float2* __restrict__ srel,
    const float* __restrict__ fin, const float* __restrict__ Win,
    const float* __restrict__ bin, const unsigned* __restrict__ bsplit,
    float* __restrict__ contrib, int E)
{
    int wid  = (blockIdx.x * 256 + threadIdx.x) >> 6;   // global wave = group
    int lane = threadIdx.x & 63;
    int g16  = wid * 16;
    int er   = lane & 15;       // A-row edge index within group
    int q    = lane >> 4;
    int e    = min(g16 + er, E - 1);
    int src  = ssrc[e];
    float2 r = srel[e];

    int c0 = (q & 1) * 8;       // c = gk&15 range for this lane (fixed over kb)
    const float4* fx = (const float4*)(fin + (size_t)src * 16 + c0);
    float4 xa = fx[0], xb = fx[1];
    float xj[8] = {xa.x, xa.y, xa.z, xa.w, xb.x, xb.y, xb.z, xb.w};

    f32x4 accHH = {0.f,0.f,0.f,0.f};
    f32x4 accLH = {0.f,0.f,0.f,0.f};
    f32x4 accHL = {0.f,0.f,0.f,0.f};

    #pragma unroll 2
    for (int kb = 0; kb < 8; ++kb) {
        int gk0 = kb * 32 + q * 8;              // == hc0 for this lane
        const float4* p1 = (const float4*)(Win + gk0);
        const float4* p2 = (const float4*)(Win + 256 + gk0);
        const float4* pb = (const float4*)(bin + gk0);
        float4 w1a = p1[0], w1b = p1[1];
        float4 w2a = p2[0], w2b = p2[1];
        float4 bba = pb[0], bbb = pb[1];
        float w1[8] = {w1a.x,w1a.y,w1a.z,w1a.w, w1b.x,w1b.y,w1b.z,w1b.w};
        float w2[8] = {w2a.x,w2a.y,w2a.z,w2a.w, w2b.x,w2b.y,w2b.z,w2b.w};
        float bv[8] = {bba.x,bba.y,bba.z,bba.w, bbb.x,bbb.y,bbb.z,bbb.w};

        union { unsigned u[4]; bf16x8 v; } Ah, Al;
        #pragma unroll
        for (int jj = 0; jj < 4; ++jj) {
            float t0 = fmaf(r.x, w1[2*jj],   fmaf(r.y, w2[2*jj],   bv[2*jj]));
            float t1 = fmaf(r.x, w1[2*jj+1], fmaf(r.y, w2[2*jj+1], bv[2*jj+1]));
            t0 = fmaxf(t0, 0.f) * xj[2*jj];
            t1 = fmaxf(t1, 0.f) * xj[2*jj+1];
            unsigned hp = cvtpk_bf16(t0, t1);
            float h0 = __uint_as_float(hp << 16);          // exact f32 of bf16 lo
            float h1 = __uint_as_float(hp & 0xFFFF0000u);  // exact f32 of bf16 hi
            Ah.u[jj] = hp;
            Al.u[jj] = cvtpk_bf16(t0 - h0, t1 - h1);
        }

        union { float4 f; bf16x8 v; } Bh, Bl;
        Bh.f = ((const float4*)bsplit)[kb * 64 + lane];
        Bl.f = ((const float4*)(bsplit + 2048))[kb * 64 + lane];

        accHH = __builtin_amdgcn_mfma_f32_16x16x32_bf16(Ah.v, Bh.v, accHH, 0, 0, 0);
        accLH = __builtin_amdgcn_mfma_f32_16x16x32_bf16(Al.v, Bh.v, accLH, 0, 0, 0);
        accHL = __builtin_amdgcn_mfma_f32_16x16x32_bf16(Ah.v, Bl.v, accHL, 0, 0, 0);
    }

    f32x4 acc = accHH + accLH + accHL;
    #pragma unroll
    for (int rr = 0; rr < 4; ++rr) {
        int erow = g16 + q * 4 + rr;            // D row = edge
        if (erow < E)
            contrib[(size_t)erow * 16 + er] = acc[rr];   // D col = o = er
    }
}

// 4 threads per node, one float4 channel-quad each. Init = bias + self-loop
// (fin[node] @ Wself), then sum grouped contributions over [start, start+cnt).
__global__ __launch_bounds__(256) void segsum_kernel(
    const int* __restrict__ start, const int* __restrict__ counts,
    const float* __restrict__ contrib,
    const float* __restrict__ fin, const float* __restrict__ wself,
    const float* __restrict__ bout, float* __restrict__ out, int n)
{
    int tid = blockIdx.x * 256 + threadIdx.x;
    int node = tid >> 2;
    int q = tid & 3;
    if (node >= n) return;

    const float4* ip = (const float4*)fin + (size_t)node * 4;
    float4 f0 = ip[0], f1 = ip[1], f2 = ip[2], f3 = ip[3];
    float xin[16] = { f0.x,f0.y,f0.z,f0.w, f1.x,f1.y,f1.z,f1.w,
                      f2.x,f2.y,f2.z,f2.w, f3.x,f3.y,f3.z,f3.w };

    float4 acc = ((const float4*)bout)[q];
    #pragma unroll
    for (int c = 0; c < 16; ++c) {
        float t = xin[c];
        float4 w = ((const float4*)wself)[c * 4 + q];
        acc.x = fmaf(t, w.x, acc.x);
        acc.y = fmaf(t, w.y, acc.y);
        acc.z = fmaf(t, w.z, acc.z);
        acc.w = fmaf(t, w.w, acc.w);
    }

    int b = start[node];
    int e = b + counts[node];
    for (int k = b; k < e; ++k) {
        float4 v = ((const float4*)contrib)[(size_t)k * 4 + q];
        acc.x += v.x; acc.y += v.y; acc.z += v.z; acc.w += v.w;
    }

    ((float4*)(out + (size_t)node * 16))[q] = acc;
}

// Edge MLP: sigmoid(relu(relu([h_s,h_d]@Wd1+b1)@Wd2+b2)@Wd3+b3)
__global__ __launch_bounds__(256) void decode_kernel(
    const int* __restrict__ ei, const float* __restrict__ h,
    const float* __restrict__ Wd1, const float* __restrict__ bd1,
    const float* __restrict__ Wd2, const float* __restrict__ bd2,
    const float* __restrict__ Wd3, const float* __restrict__ bd3,
    float* __restrict__ out, int E)
{
    int tid = blockIdx.x * 256 + threadIdx.x;
    bool valid = (tid < E);
    int e = valid ? tid : 0;
    int s = ei[e];
    int d = ei[E + e];

    const float4* hp = (const float4*)h + (size_t)s * 4;
    float4 a = hp[0], b = hp[1], c4 = hp[2], d4 = hp[3];
    float hs[16] = { a.x,a.y,a.z,a.w, b.x,b.y,b.z,b.w,
                     c4.x,c4.y,c4.z,c4.w, d4.x,d4.y,d4.z,d4.w };
    const float4* hq = (const float4*)h + (size_t)d * 4;
    float4 e0 = hq[0], e1 = hq[1], e2 = hq[2], e3 = hq[3];
    float hd[16] = { e0.x,e0.y,e0.z,e0.w, e1.x,e1.y,e1.z,e1.w,
                     e2.x,e2.y,e2.z,e2.w, e3.x,e3.y,e3.z,e3.w };

    float z1[16];
    #pragma unroll
    for (int o = 0; o < 16; ++o) z1[o] = bd1[o];
    #pragma unroll
    for (int c = 0; c < 16; ++c) {
        float u = hs[c], v = hd[c];
        #pragma unroll
        for (int o = 0; o < 16; ++o)
            z1[o] = fmaf(u, Wd1[c * 16 + o], fmaf(v, Wd1[(16 + c) * 16 + o], z1[o]));
    }

    float z2[16];
    #pragma unroll
    for (int o = 0; o < 16; ++o) z2[o] = bd2[o];
    #pragma unroll
    for (int c = 0; c < 16; ++c) {
        float t = fmaxf(z1[c], 0.f);
        #pragma unroll
        for (int o = 0; o < 16; ++o)
            z2[o] = fmaf(t, Wd2[c * 16 + o], z2[o]);
    }

    float y = bd3[0];
    #pragma unroll
    for (int c = 0; c < 16; ++c)
        y = fmaf(fmaxf(z2[c], 0.f), Wd3[c], y);

    if (valid)
        out[tid] = 1.f / (1.f + expf(-y));
}

extern "C" void kernel_launch(void* const* d_in, const int* in_sizes, int n_in,
                              void* d_out, int out_size, void* d_ws, size_t ws_size,
                              hipStream_t stream)
{
    const float* x     = (const float*)d_in[0];
    const int*   ei    = (const int*)  d_in[1];
    const float* Win1  = (const float*)d_in[2];
    const float* bin1  = (const float*)d_in[3];
    const float* Wout1 = (const float*)d_in[4];
    const float* bout1 = (const float*)d_in[5];
    const float* Win2  = (const float*)d_in[6];
    const float* bin2  = (const float*)d_in[7];
    const float* Wout2 = (const float*)d_in[8];
    const float* bout2 = (const float*)d_in[9];
    const float* Win3  = (const float*)d_in[10];
    const float* bin3  = (const float*)d_in[11];
    const float* Wout3 = (const float*)d_in[12];
    const float* bout3 = (const float*)d_in[13];
    const float* Wd1   = (const float*)d_in[14];
    const float* bd1   = (const float*)d_in[15];
    const float* Wd2   = (const float*)d_in[16];
    const float* bd2   = (const float*)d_in[17];
    const float* Wd3   = (const float*)d_in[18];
    const float* bd3   = (const float*)d_in[19];

    int n = in_sizes[0] / 18;
    int E = in_sizes[1] / 2;

    float* ws        = (float*)d_ws;
    float* pos       = ws;                          // 2n
    float* feat      = pos   + (size_t)2 * n;       // 16n
    float* hA        = feat  + (size_t)16 * n;      // 16n
    float* hB        = hA    + (size_t)16 * n;      // 16n
    float* wself     = hB    + (size_t)16 * n;      // 768
    unsigned* bsplit = (unsigned*)(wself + 768);    // 3*2*8*256 = 12288
    int* counts      = (int*)(bsplit + 12288);      // n
    int* start       = counts + n;                  // n
    int* cursor      = start + n;                   // n
    int* total       = cursor + n;                  // 4 (align)
    int* ssrc        = total + 4;                   // E
    float2* srel     = (float2*)(ssrc + E);         // E
    float* contrib   = (float*)(srel + E);          // 16E
    float* outp      = (float*)d_out;

    int nb_n = (n + 255) / 256;
    int nb_e = (E + 255) / 256;
    int nb_s = (4 * n + 255) / 256;
    int nb_m = (E + 63) / 64;      // 4 waves/block, 16 edges/wave

    prep_kernel<<<nb_n, 256, 0, stream>>>(x, pos, feat, n);
    zero_kernel<<<nb_n, 256, 0, stream>>>(counts, total, n);
    hist_kernel<<<nb_e, 256, 0, stream>>>(ei, counts, E);
    reserve_kernel<<<nb_n, 256, 0, stream>>>(counts, start, cursor, total, n);
    scatter_kernel<<<nb_e, 256, 0, stream>>>(ei, pos, cursor, ssrc, srel, E);

    WPtrs wp { bin1, Wout1, bin2, Wout2, bin3, Wout3 };
    wself_kernel<<<3, 256, 0, stream>>>(wp, wself);
    wsplit_kernel<<<3, 256, 0, stream>>>(wp, bsplit);

    // Layer 1: feat -> hA
    edge_mfma_kernel<<<nb_m, 256, 0, stream>>>(ssrc, srel, feat, Win1, bin1,
                                               bsplit + 0,    contrib, E);
    segsum_kernel<<<nb_s, 256, 0, stream>>>(start, counts, contrib, feat, wself + 0,   bout1, hA, n);
    // Layer 2: hA -> hB
    edge_mfma_kernel<<<nb_m, 256, 0, stream>>>(ssrc, srel, hA,   Win2, bin2,
                                               bsplit + 4096, contrib, E);
    segsum_kernel<<<nb_s, 256, 0, stream>>>(start, counts, contrib, hA,   wself + 256, bout2, hB, n);
    // Layer 3: hB -> hA
    edge_mfma_kernel<<<nb_m, 256, 0, stream>>>(ssrc, srel, hB,   Win3, bin3,
                                               bsplit + 8192, contrib, E);
    segsum_kernel<<<nb_s, 256, 0, stream>>>(start, counts, contrib, hB,   wself + 512, bout3, hA, n);

    decode_kernel<<<nb_e, 256, 0, stream>>>(ei, hA, Wd1, bd1, Wd2, bd2, Wd3, bd3,
                                            outp, E);
}

// Round 14
// 356.685 us; speedup vs baseline: 1.3724x; 1.1625x over previous
//
#include <hip/hip_runtime.h>
#include <hip/hip_bf16.h>
#include <math.h>

// ---------------------------------------------------------------------------
// SpatialGCN:
//  * CSR (dst-grouped, UNORDERED groups) via hist -> block-scan reservation
//    -> scatter.
//  * Per layer: edge MFMA contribution kernel (one wave = 2 groups x 16 edges,
//    (s*xj)@Wout on mfma_f32_16x16x32_bf16, 3-term bf16 split) + scalar
//    segsum (4 threads/node). Self-loops + bias folded via Wself.
//  * R11 (from R10 counters): inline-asm cvt_pk removed (compiler casts
//    schedule better, m240); 2 edge-groups/wave amortize weight loads and
//    double MFMA-chain ILP.
// ---------------------------------------------------------------------------

typedef __attribute__((ext_vector_type(8))) short bf16x8;
typedef __attribute__((ext_vector_type(4))) float f32x4;

struct WPtrs {
    const float* bin0; const float* wout0;
    const float* bin1; const float* wout1;
    const float* bin2; const float* wout2;
};

__device__ __forceinline__ unsigned short f2bf(float f) {
    union { __hip_bfloat16 h; unsigned short u; } v;
    v.h = __float2bfloat16(f);
    return v.u;
}
__device__ __forceinline__ float bf2f(unsigned short u) {
    return __uint_as_float((unsigned)u << 16);
}

// Extract packed pos (N x 2) and feat (N x 16) from x (N x 18).
__global__ __launch_bounds__(256) void prep_kernel(
    const float* __restrict__ x, float* __restrict__ pos,
    float* __restrict__ feat, int n)
{
    int i = blockIdx.x * 256 + threadIdx.x;
    if (i >= n) return;
    const float* r = x + (size_t)i * 18;
    float2 p; p.x = r[0]; p.y = r[1];
    ((float2*)pos)[i] = p;
    float4* fp = (float4*)feat + (size_t)i * 4;
    fp[0] = make_float4(r[2],  r[3],  r[4],  r[5]);
    fp[1] = make_float4(r[6],  r[7],  r[8],  r[9]);
    fp[2] = make_float4(r[10], r[11], r[12], r[13]);
    fp[3] = make_float4(r[14], r[15], r[16], r[17]);
}

__global__ __launch_bounds__(256) void zero_kernel(int* __restrict__ p, int* __restrict__ total, int n)
{
    int i = blockIdx.x * 256 + threadIdx.x;
    if (i < n) p[i] = 0;
    if (i == 0) *total = 0;
}

__global__ __launch_bounds__(256) void hist_kernel(
    const int* __restrict__ ei, int* __restrict__ counts, int E)
{
    int e = blockIdx.x * 256 + threadIdx.x;
    if (e < E) atomicAdd(&counts[ei[E + e]], 1);
}

__global__ __launch_bounds__(256) void reserve_kernel(
    const int* __restrict__ counts, int* __restrict__ start,
    int* __restrict__ cursor, int* __restrict__ total, int n)
{
    __shared__ int sdata[256];
    __shared__ int sbase;
    int t = threadIdx.x;
    int i = blockIdx.x * 256 + t;
    int c = (i < n) ? counts[i] : 0;
    sdata[t] = c;
    __syncthreads();
    #pragma unroll
    for (int off = 1; off < 256; off <<= 1) {
        int v = (t >= off) ? sdata[t - off] : 0;
        __syncthreads();
        sdata[t] += v;
        __syncthreads();
    }
    if (t == 255) sbase = atomicAdd(total, sdata[255]);
    __syncthreads();
    if (i < n) {
        int s = sbase + sdata[t] - c;
        start[i]  = s;
        cursor[i] = s;
    }
}

__global__ __launch_bounds__(256) void scatter_kernel(
    const int* __restrict__ ei, const float* __restrict__ pos,
    int* __restrict__ cursor, int* __restrict__ ssrc,
    float2* __restrict__ srel, int E)
{
    int e = blockIdx.x * 256 + threadIdx.x;
    if (e >= E) return;
    int s = ei[e];
    int d = ei[E + e];
    int p = atomicAdd(&cursor[d], 1);
    ssrc[p] = s;
    float2 ps = ((const float2*)pos)[s];
    float2 pd = ((const float2*)pos)[d];
    srel[p] = make_float2(ps.x - pd.x, ps.y - pd.y);
}

// Wself[l][c*16+o] = sum_h relu(bin[h*16+c]) * Wout[(h*16+c)*16+o]
__global__ __launch_bounds__(256) void wself_kernel(WPtrs wp, float* __restrict__ wself)
{
    int l = blockIdx.x;
    const float* bin  = (l == 0) ? wp.bin0  : (l == 1) ? wp.bin1  : wp.bin2;
    const float* wout = (l == 0) ? wp.wout0 : (l == 1) ? wp.wout1 : wp.wout2;
    int t = threadIdx.x;
    int c = t >> 4, o = t & 15;
    float acc = 0.f;
    #pragma unroll
    for (int h = 0; h < 16; ++h) {
        int hc = h * 16 + c;
        acc += fmaxf(bin[hc], 0.f) * wout[hc * 16 + o];
    }
    wself[l * 256 + t] = acc;
}

// Pre-split Wout into per-lane bf16 B-fragments (hi and lo parts).
// bsplit[(l*16 + part*8 + kb)*256 + lane*4 + j] (u32 = 2 bf16).
// Lane's B element: B[k = kb*32 + (lane>>4)*8 + 2j + {0,1}][o = lane&15].
__global__ __launch_bounds__(256) void wsplit_kernel(WPtrs wp, unsigned* __restrict__ bsplit)
{
    int l = blockIdx.x;
    const float* wout = (l == 0) ? wp.wout0 : (l == 1) ? wp.wout1 : wp.wout2;
    int tid = threadIdx.x;
    int lane = tid & 63;
    int j = tid >> 6;          // 0..3
    int o = lane & 15, q = lane >> 4;
    for (int kb = 0; kb < 8; ++kb) {
        int k0 = kb * 32 + q * 8 + 2 * j;
        float v0 = wout[k0 * 16 + o];
        float v1 = wout[(k0 + 1) * 16 + o];
        unsigned short h0 = f2bf(v0), h1 = f2bf(v1);
        unsigned short l0 = f2bf(v0 - bf2f(h0)), l1 = f2bf(v1 - bf2f(h1));
        int base = (l * 16 + kb) * 256 + lane * 4 + j;
        bsplit[base]        = (unsigned)h0 | ((unsigned)h1 << 16);
        bsplit[base + 2048] = (unsigned)l0 | ((unsigned)l1 << 16);
    }
}

// One wave = 2 groups x 16 edges. A[e][k=hc]=relu(rel.Win+bin)[hc]*xj[c].
// D = A@B via 16x16x32 bf16 MFMA, 3-term split AhiBhi+AloBhi+AhiBlo.
// A-frag: row=lane&15 (edge), k = kb*32+(lane>>4)*8+i. D: row=(lane>>4)*4+reg,
// col=lane&15. Weight loads shared across both groups (6 MFMA chains of ILP).
__global__ __launch_bounds__(256) void edge_mfma_kernel(
    const int* __restrict__ ssrc, const float2* __restrict__ srel,
    const float* __restrict__ fin, const float* __restrict__ Win,
    const float* __restrict__ bin, const unsigned* __restrict__ bsplit,
    float* __restrict__ contrib, int E)
{
    int wid  = (blockIdx.x * 256 + threadIdx.x) >> 6;
    int lane = threadIdx.x & 63;
    int base = wid * 32;
    int er   = lane & 15;
    int q    = lane >> 4;

    int eA = min(base + er,      E - 1);
    int eB = min(base + 16 + er, E - 1);
    int sA = ssrc[eA], sB = ssrc[eB];
    float2 rA = srel[eA], rB = srel[eB];

    int c0 = (q & 1) * 8;          // c = (q*8+i) & 15 = c0+i
    const float4* fxA = (const float4*)(fin + (size_t)sA * 16 + c0);
    float4 a0 = fxA[0], a1 = fxA[1];
    float xjA[8] = {a0.x,a0.y,a0.z,a0.w, a1.x,a1.y,a1.z,a1.w};
    const float4* fxB = (const float4*)(fin + (size_t)sB * 16 + c0);
    float4 b0 = fxB[0], b1 = fxB[1];
    float xjB[8] = {b0.x,b0.y,b0.z,b0.w, b1.x,b1.y,b1.z,b1.w};

    f32x4 accA_HH = {0.f,0.f,0.f,0.f}, accA_LH = accA_HH, accA_HL = accA_HH;
    f32x4 accB_HH = accA_HH, accB_LH = accA_HH, accB_HL = accA_HH;

    #pragma unroll 2
    for (int kb = 0; kb < 8; ++kb) {
        int gk0 = kb * 32 + q * 8;
        const float4* p1 = (const float4*)(Win + gk0);
        const float4* p2 = (const float4*)(Win + 256 + gk0);
        const float4* pb = (const float4*)(bin + gk0);
        float4 w1a = p1[0], w1b = p1[1];
        float4 w2a = p2[0], w2b = p2[1];
        float4 bba = pb[0], bbb = pb[1];
        float w1[8] = {w1a.x,w1a.y,w1a.z,w1a.w, w1b.x,w1b.y,w1b.z,w1b.w};
        float w2[8] = {w2a.x,w2a.y,w2a.z,w2a.w, w2b.x,w2b.y,w2b.z,w2b.w};
        float bv[8] = {bba.x,bba.y,bba.z,bba.w, bbb.x,bbb.y,bbb.z,bbb.w};

        union { unsigned short s[8]; bf16x8 v; } AhA, AlA, AhB, AlB;
        #pragma unroll
        for (int i = 0; i < 8; ++i) {
            float tA = fmaf(rA.x, w1[i], fmaf(rA.y, w2[i], bv[i]));
            tA = fmaxf(tA, 0.f) * xjA[i];
            unsigned short hA = f2bf(tA);
            AhA.s[i] = hA;
            AlA.s[i] = f2bf(tA - bf2f(hA));
            float tB = fmaf(rB.x, w1[i], fmaf(rB.y, w2[i], bv[i]));
            tB = fmaxf(tB, 0.f) * xjB[i];
            unsigned short hB = f2bf(tB);
            AhB.s[i] = hB;
            AlB.s[i] = f2bf(tB - bf2f(hB));
        }

        union { float4 f; bf16x8 v; } Bh, Bl;
        Bh.f = ((const float4*)bsplit)[kb * 64 + lane];
        Bl.f = ((const float4*)(bsplit + 2048))[kb * 64 + lane];

        accA_HH = __builtin_amdgcn_mfma_f32_16x16x32_bf16(AhA.v, Bh.v, accA_HH, 0, 0, 0);
        accB_HH = __builtin_amdgcn_mfma_f32_16x16x32_bf16(AhB.v, Bh.v, accB_HH, 0, 0, 0);
        accA_LH = __builtin_amdgcn_mfma_f32_16x16x32_bf16(AlA.v, Bh.v, accA_LH, 0, 0, 0);
        accB_LH = __builtin_amdgcn_mfma_f32_16x16x32_bf16(AlB.v, Bh.v, accB_LH, 0, 0, 0);
        accA_HL = __builtin_amdgcn_mfma_f32_16x16x32_bf16(AhA.v, Bl.v, accA_HL, 0, 0, 0);
        accB_HL = __builtin_amdgcn_mfma_f32_16x16x32_bf16(AhB.v, Bl.v, accB_HL, 0, 0, 0);
    }

    f32x4 accA = accA_HH + accA_LH + accA_HL;
    f32x4 accB = accB_HH + accB_LH + accB_HL;
    #pragma unroll
    for (int rr = 0; rr < 4; ++rr) {
        int rowA = base + q * 4 + rr;
        if (rowA < E) contrib[(size_t)rowA * 16 + er] = accA[rr];
        int rowB = base + 16 + q * 4 + rr;
        if (rowB < E) contrib[(size_t)rowB * 16 + er] = accB[rr];
    }
}

// 4 threads per node, one float4 channel-quad each. Init = bias + self-loop
// (fin[node] @ Wself), then sum grouped contributions over [start, start+cnt).
__global__ __launch_bounds__(256) void segsum_kernel(
    const int* __restrict__ start, const int* __restrict__ counts,
    const float* __restrict__ contrib,
    const float* __restrict__ fin, const float* __restrict__ wself,
    const float* __restrict__ bout, float* __restrict__ out, int n)
{
    int tid = blockIdx.x * 256 + threadIdx.x;
    int node = tid >> 2;
    int q = tid & 3;
    if (node >= n) return;

    const float4* ip = (const float4*)fin + (size_t)node * 4;
    float4 f0 = ip[0], f1 = ip[1], f2 = ip[2], f3 = ip[3];
    float xin[16] = { f0.x,f0.y,f0.z,f0.w, f1.x,f1.y,f1.z,f1.w,
                      f2.x,f2.y,f2.z,f2.w, f3.x,f3.y,f3.z,f3.w };

    float4 acc = ((const float4*)bout)[q];
    #pragma unroll
    for (int c = 0; c < 16; ++c) {
        float t = xin[c];
        float4 w = ((const float4*)wself)[c * 4 + q];
        acc.x = fmaf(t, w.x, acc.x);
        acc.y = fmaf(t, w.y, acc.y);
        acc.z = fmaf(t, w.z, acc.z);
        acc.w = fmaf(t, w.w, acc.w);
    }

    int b = start[node];
    int e = b + counts[node];
    for (int k = b; k < e; ++k) {
        float4 v = ((const float4*)contrib)[(size_t)k * 4 + q];
        acc.x += v.x; acc.y += v.y; acc.z += v.z; acc.w += v.w;
    }

    ((float4*)(out + (size_t)node * 16))[q] = acc;
}

// Edge MLP: sigmoid(relu(relu([h_s,h_d]@Wd1+b1)@Wd2+b2)@Wd3+b3)
__global__ __launch_bounds__(256) void decode_kernel(
    const int* __restrict__ ei, const float* __restrict__ h,
    const float* __restrict__ Wd1, const float* __restrict__ bd1,
    const float* __restrict__ Wd2, const float* __restrict__ bd2,
    const float* __restrict__ Wd3, const float* __restrict__ bd3,
    float* __restrict__ out, int E)
{
    int tid = blockIdx.x * 256 + threadIdx.x;
    bool valid = (tid < E);
    int e = valid ? tid : 0;
    int s = ei[e];
    int d = ei[E + e];

    const float4* hp = (const float4*)h + (size_t)s * 4;
    float4 a = hp[0], b = hp[1], c4 = hp[2], d4 = hp[3];
    float hs[16] = { a.x,a.y,a.z,a.w, b.x,b.y,b.z,b.w,
                     c4.x,c4.y,c4.z,c4.w, d4.x,d4.y,d4.z,d4.w };
    const float4* hq = (const float4*)h + (size_t)d * 4;
    float4 e0 = hq[0], e1 = hq[1], e2 = hq[2], e3 = hq[3];
    float hd[16] = { e0.x,e0.y,e0.z,e0.w, e1.x,e1.y,e1.z,e1.w,
                     e2.x,e2.y,e2.z,e2.w, e3.x,e3.y,e3.z,e3.w };

    float z1[16];
    #pragma unroll
    for (int o = 0; o < 16; ++o) z1[o] = bd1[o];
    #pragma unroll
    for (int c = 0; c < 16; ++c) {
        float u = hs[c], v = hd[c];
        #pragma unroll
        for (int o = 0; o < 16; ++o)
            z1[o] = fmaf(u, Wd1[c * 16 + o], fmaf(v, Wd1[(16 + c) * 16 + o], z1[o]));
    }

    float z2[16];
    #pragma unroll
    for (int o = 0; o < 16; ++o) z2[o] = bd2[o];
    #pragma unroll
    for (int c = 0; c < 16; ++c) {
        float t = fmaxf(z1[c], 0.f);
        #pragma unroll
        for (int o = 0; o < 16; ++o)
            z2[o] = fmaf(t, Wd2[c * 16 + o], z2[o]);
    }

    float y = bd3[0];
    #pragma unroll
    for (int c = 0; c < 16; ++c)
        y = fmaf(fmaxf(z2[c], 0.f), Wd3[c], y);

    if (valid)
        out[tid] = 1.f / (1.f + expf(-y));
}

extern "C" void kernel_launch(void* const* d_in, const int* in_sizes, int n_in,
                              void* d_out, int out_size, void* d_ws, size_t ws_size,
                              hipStream_t stream)
{
    const float* x     = (const float*)d_in[0];
    const int*   ei    = (const int*)  d_in[1];
    const float* Win1  = (const float*)d_in[2];
    const float* bin1  = (const float*)d_in[3];
    const float* Wout1 = (const float*)d_in[4];
    const float* bout1 = (const float*)d_in[5];
    const float* Win2  = (const float*)d_in[6];
    const float* bin2  = (const float*)d_in[7];
    const float* Wout2 = (const float*)d_in[8];
    const float* bout2 = (const float*)d_in[9];
    const float* Win3  = (const float*)d_in[10];
    const float* bin3  = (const float*)d_in[11];
    const float* Wout3 = (const float*)d_in[12];
    const float* bout3 = (const float*)d_in[13];
    const float* Wd1   = (const float*)d_in[14];
    const float* bd1   = (const float*)d_in[15];
    const float* Wd2   = (const float*)d_in[16];
    const float* bd2   = (const float*)d_in[17];
    const float* Wd3   = (const float*)d_in[18];
    const float* bd3   = (const float*)d_in[19];

    int n = in_sizes[0] / 18;
    int E = in_sizes[1] / 2;

    float* ws        = (float*)d_ws;
    float* pos       = ws;                          // 2n
    float* feat      = pos   + (size_t)2 * n;       // 16n
    float* hA        = feat  + (size_t)16 * n;      // 16n
    float* hB        = hA    + (size_t)16 * n;      // 16n
    float* wself     = hB    + (size_t)16 * n;      // 768
    unsigned* bsplit = (unsigned*)(wself + 768);    // 3*2*8*256 = 12288
    int* counts      = (int*)(bsplit + 12288);      // n
    int* start       = counts + n;                  // n
    int* cursor      = start + n;                   // n
    int* total       = cursor + n;                  // 4 (align)
    int* ssrc        = total + 4;                   // E
    float2* srel     = (float2*)(ssrc + E);         // E
    float* contrib   = (float*)(srel + E);          // 16E
    float* outp      = (float*)d_out;

    int nb_n = (n + 255) / 256;
    int nb_e = (E + 255) / 256;
    int nb_s = (4 * n + 255) / 256;
    int nb_m = (E + 127) / 128;    // 4 waves/block, 32 edges/wave

    prep_kernel<<<nb_n, 256, 0, stream>>>(x, pos, feat, n);
    zero_kernel<<<nb_n, 256, 0, stream>>>(counts, total, n);
    hist_kernel<<<nb_e, 256, 0, stream>>>(ei, counts, E);
    reserve_kernel<<<nb_n, 256, 0, stream>>>(counts, start, cursor, total, n);
    scatter_kernel<<<nb_e, 256, 0, stream>>>(ei, pos, cursor, ssrc, srel, E);

    WPtrs wp { bin1, Wout1, bin2, Wout2, bin3, Wout3 };
    wself_kernel<<<3, 256, 0, stream>>>(wp, wself);
    wsplit_kernel<<<3, 256, 0, stream>>>(wp, bsplit);

    // Layer 1: feat -> hA
    edge_mfma_kernel<<<nb_m, 256, 0, stream>>>(ssrc, srel, feat, Win1, bin1,
                                               bsplit + 0,    contrib, E);
    segsum_kernel<<<nb_s, 256, 0, stream>>>(start, counts, contrib, feat, wself + 0,   bout1, hA, n);
    // Layer 2: hA -> hB
    edge_mfma_kernel<<<nb_m, 256, 0, stream>>>(ssrc, srel, hA,   Win2, bin2,
                                               bsplit + 4096, contrib, E);
    segsum_kernel<<<nb_s, 256, 0, stream>>>(start, counts, contrib, hA,   wself + 256, bout2, hB, n);
    // Layer 3: hB -> hA
    edge_mfma_kernel<<<nb_m, 256, 0, stream>>>(ssrc, srel, hB,   Win3, bin3,
                                               bsplit + 8192, contrib, E);
    segsum_kernel<<<nb_s, 256, 0, stream>>>(start, counts, contrib, hB,   wself + 512, bout3, hA, n);

    decode_kernel<<<nb_e, 256, 0, stream>>>(ei, hA, Wd1, bd1, Wd2, bd2, Wd3, bd3,
                                            outp, E);
}